// Round 5
// baseline (401.164 us; speedup 1.0000x reference)
//
#include <hip/hip_runtime.h>

typedef __attribute__((ext_vector_type(8))) __bf16 bf16x8;
typedef __attribute__((ext_vector_type(4))) float f32x4;

__device__ __forceinline__ unsigned short f2bf(float x) {
  union { float f; unsigned int u; } v; v.f = x;
  unsigned int r = v.u + 0x7fffu + ((v.u >> 16) & 1u);
  return (unsigned short)(r >> 16);
}
__device__ __forceinline__ float bf2f(unsigned short x) {
  union { unsigned int u; float f; } v; v.u = ((unsigned int)x) << 16;
  return v.f;
}
__device__ __forceinline__ void g2l16(const void* g, void* l) {
  __builtin_amdgcn_global_load_lds((const __attribute__((address_space(1))) void*)g,
                                   (__attribute__((address_space(3))) void*)l, 16, 0, 0);
}

#define BARX()                                  \
  do {                                          \
    asm volatile("" ::: "memory");              \
    __builtin_amdgcn_s_barrier();               \
    asm volatile("" ::: "memory");              \
  } while (0)

// ---------------- fused input prep ----------------
// blocks [0,8192):        x fp32 -> bf16            (4 elems/thread)
// blocks [8192,11264):    wqkv [2048,6144] -> transposed bf16 [6144,2048]
// blocks [11264,12288):   wout [2048,2048] -> transposed bf16 [2048,2048]
__global__ __launch_bounds__(256) void prep_k(const float* __restrict__ x,
                                              const float* __restrict__ wq,
                                              const float* __restrict__ wo,
                                              unsigned short* __restrict__ xb,
                                              unsigned short* __restrict__ wqT,
                                              unsigned short* __restrict__ woT) {
  __shared__ unsigned short t[64][65];
  const int b = blockIdx.x;
  if (b < 8192) {
    int i = b * 256 + threadIdx.x;
    float4 v = ((const float4*)x)[i];
    ushort4 o;
    o.x = f2bf(v.x); o.y = f2bf(v.y); o.z = f2bf(v.z); o.w = f2bf(v.w);
    ((ushort4*)xb)[i] = o;
    return;
  }
  const float* in; unsigned short* out; int C, c0, r0;
  const int R = 2048;
  if (b < 11264) { int bb = b - 8192;  in = wq; out = wqT; C = 6144; c0 = (bb % 96) * 64; r0 = (bb / 96) * 64; }
  else           { int bb = b - 11264; in = wo; out = woT; C = 2048; c0 = (bb & 31) * 64; r0 = (bb >> 5) * 64; }
  const int tx = threadIdx.x & 63, tg = threadIdx.x >> 6;
#pragma unroll
  for (int i = 0; i < 16; i++) {
    int r = i * 4 + tg;
    t[r][tx] = f2bf(in[(size_t)(r0 + r) * C + c0 + tx]);
  }
  __syncthreads();
#pragma unroll
  for (int i = 0; i < 16; i++) {
    int c = i * 4 + tg;
    out[(size_t)(c0 + c) * R + r0 + tx] = t[tx][c];
  }
}

// ---------------- GEMM: C[M,N] = A[M,K](bf16) @ BT[N,K](bf16)^T ----------------
// R0 kernel restored verbatim (measured 123.4 us for QKV, VGPR 84, no spill).
// R1-R4 lesson: the 256^2 8-phase template is blocked on this geometry by the
// 384-block/1-per-CU 0.75 tail factor + barrier-lockstep LDS/MFMA serialization;
// its reg budget (244/wave) forbids both co-residency and cross-phase prefetch.
// 128x128 tile, BK=64, XOR-swizzled conflict-free LDS.
// EPI=0 (qkv): fused epilogue — q/k: RoPE via [row][col] LDS tile (stride 130);
//   v: acc -> TRANSPOSED LDS tile [d][s] (stride 136) -> coalesced vt [B,H,D,S].
// EPI=1: plain fp32 store (out projection).
template <int EPI>
__global__ __launch_bounds__(256) void gemm_bt_k(const unsigned short* __restrict__ A,
                                                 const unsigned short* __restrict__ BT,
                                                 int K, int N,
                                                 float* __restrict__ outF,
                                                 unsigned short* __restrict__ oq,
                                                 unsigned short* __restrict__ ok,
                                                 unsigned short* __restrict__ ov) {
  __shared__ __align__(16) unsigned short smem[17408];   // gemm 2x8192 | epi 128x130 or 128x136
  unsigned short* lA = smem;
  unsigned short* lB = smem + 8192;
  const int tid = threadIdx.x;
  const int w = tid >> 6, lane = tid & 63;
  const int quad = lane >> 4, l16 = lane & 15;
  const int m0 = blockIdx.y * 128, n0 = blockIdx.x * 128;
  const int wm = (w >> 1) * 64, wn = (w & 1) * 64;
  f32x4 acc[4][4] = {};
  const int srow = tid >> 3;                     // staging row 0..31 (+j*32)
  const int schunk = (tid & 7) ^ (srow & 7);     // swizzled logical chunk
  const unsigned short* gA = A + (size_t)(m0 + srow) * K + schunk * 8;
  const unsigned short* gB = BT + (size_t)(n0 + srow) * K + schunk * 8;
  char* ldA = (char*)lA + tid * 16;
  char* ldB = (char*)lB + tid * 16;
  const size_t rskip = (size_t)32 * K;
  for (int k0 = 0; k0 < K; k0 += 64) {
#pragma unroll
    for (int j = 0; j < 4; j++) {
      g2l16(gA + k0 + j * rskip, ldA + j * 4096);
      g2l16(gB + k0 + j * rskip, ldB + j * 4096);
    }
    __syncthreads();
#pragma unroll
    for (int ks = 0; ks < 2; ks++) {
      bf16x8 af[4], bfv[4];
#pragma unroll
      for (int i = 0; i < 4; i++)
        af[i] = *(const bf16x8*)((const char*)lA + (size_t)(wm + i * 16 + l16) * 128 +
                                 ((size_t)((ks * 4 + quad) ^ (l16 & 7)) * 16));
#pragma unroll
      for (int j = 0; j < 4; j++)
        bfv[j] = *(const bf16x8*)((const char*)lB + (size_t)(wn + j * 16 + l16) * 128 +
                                  ((size_t)((ks * 4 + quad) ^ (l16 & 7)) * 16));
#pragma unroll
      for (int i = 0; i < 4; i++)
#pragma unroll
        for (int j = 0; j < 4; j++)
          acc[i][j] = __builtin_amdgcn_mfma_f32_16x16x32_bf16(af[i], bfv[j], acc[i][j], 0, 0, 0);
    }
    __syncthreads();
  }
  if (EPI == 0) {
    const int which = n0 >> 11;          // 0=q 1=k 2=v
    const int h = (n0 >> 7) & 15;        // tile spans exactly one head
    const int bi2 = m0 >> 11, s0 = m0 & 2047;   // whole tile is one batch
    if (which < 2) {
#pragma unroll
      for (int i = 0; i < 4; i++)
#pragma unroll
        for (int r = 0; r < 4; r++) {
          int row = wm + i * 16 + quad * 4 + r;
#pragma unroll
          for (int j = 0; j < 4; j++)
            smem[row * 130 + wn + j * 16 + l16] = f2bf(acc[i][j][r]);
        }
      __syncthreads();
      unsigned short* dst = (which == 0) ? oq : ok;
      const float scale = (which == 0) ? 0.08838834764831845f : 1.0f;
      const int d = tid & 63, tg = tid >> 6;
      const float fr = exp2f(-(float)d * (13.287712379549449f / 64.0f));
      const size_t hb = ((size_t)(bi2 * 16 + h) * 2048 + s0) * 128;
#pragma unroll
      for (int i = 0; i < 32; i++) {
        int r = i * 4 + tg;
        float a = bf2f(smem[r * 130 + d]);
        float bb = bf2f(smem[r * 130 + 64 + d]);
        float sn, cs;
        __sincosf((float)(s0 + r) * fr, &sn, &cs);
        dst[hb + (size_t)r * 128 + d]      = f2bf((a * cs - bb * sn) * scale);
        dst[hb + (size_t)r * 128 + 64 + d] = f2bf((bb * cs + a * sn) * scale);
      }
    } else {
#pragma unroll
      for (int i = 0; i < 4; i++)
#pragma unroll
        for (int j = 0; j < 4; j++) {
          int row = wm + i * 16 + quad * 4;       // s base (r=0..3 consecutive)
          int col = wn + j * 16 + l16;            // d
          ushort4 t4;
          t4.x = f2bf(acc[i][j][0]); t4.y = f2bf(acc[i][j][1]);
          t4.z = f2bf(acc[i][j][2]); t4.w = f2bf(acc[i][j][3]);
          *(ushort4*)&smem[col * 136 + row] = t4; // 8B-aligned ds_write_b64
        }
      __syncthreads();
      const int sc = tid & 15, dbase = tid >> 4;
      const size_t vrb = ((size_t)(bi2 * 16 + h) * 128) * 2048 + s0;
#pragma unroll
      for (int v = 0; v < 8; v++) {
        int d = dbase + v * 16;
        uint4 val = *(const uint4*)&smem[d * 136 + sc * 8];
        *(uint4*)(ov + vrb + (size_t)d * 2048 + sc * 8) = val;
      }
    }
  } else {
#pragma unroll
    for (int i = 0; i < 4; i++)
#pragma unroll
      for (int r = 0; r < 4; r++) {
        size_t rowb = (size_t)(m0 + wm + i * 16 + quad * 4 + r) * N;
#pragma unroll
        for (int j = 0; j < 4; j++)
          outF[rowb + n0 + wn + j * 16 + l16] = acc[i][j][r];
      }
  }
}

// ---------------- flash attention v2: counted-vmcnt K/V pipeline ----------------
// R5 change vs R0: the per-tile {stage -> __syncthreads (vmcnt(0)!) -> compute}
// full-drain is replaced by a software pipeline: stage K(kt+1) right after QK's
// barrier, stage V(kt+1) after PV's barrier, and wait with COUNTED vmcnt(4)
// (T3/T4: never drain to 0 mid-loop). 4 raw barriers/tile, LDS unchanged
// (50.4 KB), compute bodies byte-identical to R0's proven code.
// Hazards: K(kt+1) overwrites lK only after C-barrier (QK(kt) reads done);
// V(kt+1) after F-barrier (PV(kt) done). RAW: A waits K(kt) [vmcnt(4) leaves
// V(kt)'s 4 ops in flight]; D waits V(kt) [leaves K(kt+1)'s 4; vmcnt(0) on the
// last tile where no K was staged]. Barriers are block-uniform (act gates only
// compute, never barriers/stages).
__global__ __launch_bounds__(256, 2) void attn_k(const unsigned short* __restrict__ qb,
                                                 const unsigned short* __restrict__ kb,
                                                 const unsigned short* __restrict__ vt,
                                                 unsigned short* __restrict__ ob) {
  __shared__ __align__(16) unsigned short lK[64 * 128];   // chunk l = row*16 + (cg^row&15)
  __shared__ __align__(16) unsigned short lV[128 * 64];   // chunk l = d*8 + (sg^d&7)
  __shared__ __align__(16) __bf16 pbuf[4][32 * 72];       // wave-private P (stride 72)
  const int tid = threadIdx.x;
  const int w = tid >> 6, lane = tid & 63;
  const int quad = lane >> 4, l16 = lane & 15;
  // complementary qt pairing for causal load balance
  const int qt = (blockIdx.y < 16) ? (int)blockIdx.x : 15 - (int)blockIdx.x;
  const int bh = blockIdx.y;
  const int bi = bh >> 4, h = bh & 15;
  const int q0w = qt * 128 + w * 32;
  const unsigned short* qp = qb + (size_t)bh * 2048 * 128;
  const unsigned short* kp = kb + (size_t)bh * 2048 * 128;
  const unsigned short* vp = vt + (size_t)bh * 128 * 2048;
  __bf16* pw = pbuf[w];

  // Q fragments: 2 row-groups x 4 k-chunks, A-layout
  bf16x8 qf[2][4];
#pragma unroll
  for (int rg = 0; rg < 2; rg++) {
    const unsigned short* qr = qp + (size_t)(q0w + rg * 16 + l16) * 128 + quad * 8;
#pragma unroll
    for (int st = 0; st < 4; st++) qf[rg][st] = *(const bf16x8*)(qr + st * 32);
  }
  f32x4 o[2][8] = {};
  f32x4 lsum[2] = {};

  // staging index precompute (chunk l = j*256 + tid)
  const int krow = tid >> 4;                       // + j*16
  const int kcg = (tid & 15) ^ krow;               // row&15 == krow (krow<16)
  const int vd = tid >> 3;                         // + j*32
  const int vsg = (tid & 7) ^ ((tid >> 3) & 7);
  unsigned short* lKdst = lK + (size_t)tid * 8;    // + j*2048 shorts
  unsigned short* lVdst = lV + (size_t)tid * 8;

  const int nkt = 2 * qt + 2;                      // block-uniform
  const int myNkt = (q0w + 31) / 64 + 1;           // this wave's causal bound

  // prologue: stage K(0) then V(0)  (4+4 vmem ops per thread in flight)
#pragma unroll
  for (int j = 0; j < 4; j++)
    g2l16(kp + (size_t)(j * 16 + krow) * 128 + kcg * 8, lKdst + j * 2048);
#pragma unroll
  for (int j = 0; j < 4; j++)
    g2l16(vp + (size_t)(j * 32 + vd) * 2048 + vsg * 8, lVdst + j * 2048);

  for (int kt = 0; kt < nkt; kt++) {
    const int kt0 = kt * 64;
    // A: wait K(kt) (drain to 4: V(kt) stays in flight), publish to block
    asm volatile("s_waitcnt vmcnt(4)" ::: "memory");
    BARX();
    const bool act = (kt < myNkt);
    f32x4 sc[2][4] = {};
    if (act) {
      // S = Q K^T (pre-scaled): 32 q-rows x 64 k-cols
#pragma unroll
      for (int ct = 0; ct < 4; ct++) {
        const int nrow = ct * 16 + l16;
#pragma unroll
        for (int st = 0; st < 4; st++) {
          bf16x8 kf = *(const bf16x8*)(lK + ((size_t)nrow * 16 + ((st * 4 + quad) ^ l16)) * 8);
          sc[0][ct] = __builtin_amdgcn_mfma_f32_16x16x32_bf16(qf[0][st], kf, sc[0][ct], 0, 0, 0);
          sc[1][ct] = __builtin_amdgcn_mfma_f32_16x16x32_bf16(qf[1][st], kf, sc[1][ct], 0, 0, 0);
        }
      }
    }
    BARX();   // C: all QK reads of lK complete across the block
    if (kt + 1 < nkt) {
#pragma unroll
      for (int j = 0; j < 4; j++)
        g2l16(kp + (size_t)(kt0 + 64 + j * 16 + krow) * 128 + kcg * 8, lKdst + j * 2048);
    }
    // softmax (VALU + wave-private pbuf only) — overlaps V(kt)'s in-flight loads
    bf16x8 pf[2][2];
    if (act) {
      const bool needmask = (kt == myNkt - 1);
#pragma unroll
      for (int rg = 0; rg < 2; rg++)
#pragma unroll
        for (int ct = 0; ct < 4; ct++) {
          const int col = kt0 + ct * 16 + l16;
          const int rowb = q0w + rg * 16 + quad * 4;
#pragma unroll
          for (int r = 0; r < 4; r++) {
            float s = sc[rg][ct][r];
            if (needmask && col > rowb + r) s = -1e30f;
            float e = __expf(s);
            lsum[rg][r] += e;
            pw[(rg * 16 + quad * 4 + r) * 72 + ct * 16 + l16] = (__bf16)e;
          }
        }
#pragma unroll
      for (int rg = 0; rg < 2; rg++)
#pragma unroll
        for (int sb = 0; sb < 2; sb++)
          pf[rg][sb] = *(const bf16x8*)(pw + (rg * 16 + l16) * 72 + sb * 32 + quad * 8);
    }
    // D: wait V(kt) (K(kt+1)'s 4 ops stay in flight; last tile drains fully)
    if (kt + 1 < nkt) asm volatile("s_waitcnt vmcnt(4)" ::: "memory");
    else              asm volatile("s_waitcnt vmcnt(0)" ::: "memory");
    BARX();
    if (act) {
      // O += P @ V
#pragma unroll
      for (int dt = 0; dt < 8; dt++) {
#pragma unroll
        for (int sb = 0; sb < 2; sb++) {
          bf16x8 vf = *(const bf16x8*)(lV +
              ((size_t)(dt * 16 + l16) * 8 + ((sb * 4 + quad) ^ (l16 & 7))) * 8);
          o[0][dt] = __builtin_amdgcn_mfma_f32_16x16x32_bf16(pf[0][sb], vf, o[0][dt], 0, 0, 0);
          o[1][dt] = __builtin_amdgcn_mfma_f32_16x16x32_bf16(pf[1][sb], vf, o[1][dt], 0, 0, 0);
        }
      }
    }
    BARX();   // F: all PV reads of lV complete across the block
    if (kt + 1 < nkt) {
#pragma unroll
      for (int j = 0; j < 4; j++)
        g2l16(vp + (size_t)(j * 32 + vd) * 2048 + kt0 + 64 + vsg * 8, lVdst + j * 2048);
    }
  }
  // reduce l across the 16 col-lanes (once per wave)
#pragma unroll
  for (int m = 1; m < 16; m <<= 1)
#pragma unroll
    for (int rg = 0; rg < 2; rg++)
#pragma unroll
      for (int r = 0; r < 4; r++)
        lsum[rg][r] += __shfl_xor(lsum[rg][r], m, 64);
  float inv[2][4];
#pragma unroll
  for (int rg = 0; rg < 2; rg++)
#pragma unroll
    for (int r = 0; r < 4; r++) inv[rg][r] = 1.0f / lsum[rg][r];
#pragma unroll
  for (int rg = 0; rg < 2; rg++)
#pragma unroll
    for (int dt = 0; dt < 8; dt++)
#pragma unroll
      for (int r = 0; r < 4; r++)
        ob[(size_t)(bi * 2048 + q0w + rg * 16 + quad * 4 + r) * 2048 + h * 128 + dt * 16 + l16] =
            f2bf(o[rg][dt][r] * inv[rg][r]);
}

extern "C" void kernel_launch(void* const* d_in, const int* in_sizes, int n_in,
                              void* d_out, int out_size, void* d_ws, size_t ws_size,
                              hipStream_t stream) {
  const float* x = (const float*)d_in[0];
  const float* wqkv = (const float*)d_in[1];
  const float* wout = (const float*)d_in[2];
  // d_in[3] = mask, unused (causal analytically)
  char* ws = (char*)d_ws;
  const size_t MiB = 1ull << 20;
  unsigned short* xb    = (unsigned short*)(ws + 0);         // [4096,2048] bf16   16 MiB
  unsigned short* wqkvT = (unsigned short*)(ws + 16 * MiB);  // [6144,2048] bf16   24 MiB
  unsigned short* woutT = (unsigned short*)(ws + 40 * MiB);  // [2048,2048] bf16    8 MiB
  unsigned short* qb    = (unsigned short*)(ws + 48 * MiB);  // [32,2048,128] bf16 16 MiB
  unsigned short* kb    = (unsigned short*)(ws + 64 * MiB);  // [32,2048,128]      16 MiB
  unsigned short* vtb   = (unsigned short*)(ws + 80 * MiB);  // [32,128,2048]      16 MiB
  unsigned short* attnb = (unsigned short*)(ws + 96 * MiB);  // [4096,2048] bf16   16 MiB
  float* outF = (float*)d_out;

  prep_k<<<12288, 256, 0, stream>>>(x, wqkv, wout, xb, wqkvT, woutT);
  gemm_bt_k<0><<<dim3(48, 32), 256, 0, stream>>>(xb, wqkvT, 2048, 6144, nullptr, qb, kb, vtb);
  attn_k<<<dim3(16, 32), 256, 0, stream>>>(qb, kb, vtb, attnb);
  gemm_bt_k<1><<<dim3(16, 32), 256, 0, stream>>>(attnb, woutT, 2048, 2048, outF,
                                                 nullptr, nullptr, nullptr);
}

// Round 6
// 389.506 us; speedup vs baseline: 1.0299x; 1.0299x over previous
//
#include <hip/hip_runtime.h>

typedef __attribute__((ext_vector_type(8))) __bf16 bf16x8;
typedef __attribute__((ext_vector_type(4))) float f32x4;

__device__ __forceinline__ unsigned short f2bf(float x) {
  union { float f; unsigned int u; } v; v.f = x;
  unsigned int r = v.u + 0x7fffu + ((v.u >> 16) & 1u);
  return (unsigned short)(r >> 16);
}
__device__ __forceinline__ float bf2f(unsigned short x) {
  union { unsigned int u; float f; } v; v.u = ((unsigned int)x) << 16;
  return v.f;
}
__device__ __forceinline__ void g2l16(const void* g, void* l) {
  __builtin_amdgcn_global_load_lds((const __attribute__((address_space(1))) void*)g,
                                   (__attribute__((address_space(3))) void*)l, 16, 0, 0);
}

#define BARX()                                  \
  do {                                          \
    asm volatile("" ::: "memory");              \
    __builtin_amdgcn_s_barrier();               \
    asm volatile("" ::: "memory");              \
  } while (0)

// ---------------- fused input prep ----------------
// blocks [0,8192):        x fp32 -> bf16            (float4 -> ushort4)
// blocks [8192,11264):    wqkv [2048,6144] -> transposed bf16 [6144,2048]
// blocks [11264,12288):   wout [2048,2048] -> transposed bf16 [2048,2048]
// R6: transpose legs vectorized (G13) — float4 loads (16B/lane), ushort4 stores
// (8B/lane) instead of scalar fp32/ushort.
__global__ __launch_bounds__(256) void prep_k(const float* __restrict__ x,
                                              const float* __restrict__ wq,
                                              const float* __restrict__ wo,
                                              unsigned short* __restrict__ xb,
                                              unsigned short* __restrict__ wqT,
                                              unsigned short* __restrict__ woT) {
  __shared__ unsigned short t[64][65];
  const int b = blockIdx.x;
  if (b < 8192) {
    int i = b * 256 + threadIdx.x;
    float4 v = ((const float4*)x)[i];
    ushort4 o;
    o.x = f2bf(v.x); o.y = f2bf(v.y); o.z = f2bf(v.z); o.w = f2bf(v.w);
    ((ushort4*)xb)[i] = o;
    return;
  }
  const float* in; unsigned short* out; int C, c0, r0;
  const int R = 2048;
  if (b < 11264) { int bb = b - 8192;  in = wq; out = wqT; C = 6144; c0 = (bb % 96) * 64; r0 = (bb / 96) * 64; }
  else           { int bb = b - 11264; in = wo; out = woT; C = 2048; c0 = (bb & 31) * 64; r0 = (bb >> 5) * 64; }
  const int tx16 = threadIdx.x & 15, rr4 = threadIdx.x >> 4;   // 16 lanes x 16 rows
#pragma unroll
  for (int p = 0; p < 4; p++) {
    const int r = p * 16 + rr4;
    float4 v = *(const float4*)&in[(size_t)(r0 + r) * C + c0 + tx16 * 4];
    t[r][tx16 * 4 + 0] = f2bf(v.x);
    t[r][tx16 * 4 + 1] = f2bf(v.y);
    t[r][tx16 * 4 + 2] = f2bf(v.z);
    t[r][tx16 * 4 + 3] = f2bf(v.w);
  }
  __syncthreads();
#pragma unroll
  for (int p = 0; p < 4; p++) {
    const int c = p * 16 + rr4;
    ushort4 o4;
    o4.x = t[tx16 * 4 + 0][c];
    o4.y = t[tx16 * 4 + 1][c];
    o4.z = t[tx16 * 4 + 2][c];
    o4.w = t[tx16 * 4 + 3][c];
    *(ushort4*)&out[(size_t)(c0 + c) * R + r0 + tx16 * 4] = o4;
  }
}

// ---------------- GEMM: C[M,N] = A[M,K](bf16) @ BT[N,K](bf16)^T ----------------
// R0 kernel verbatim (measured 123-125 us QKV, VGPR 84, no spill, 837 TF —
// at the m97-structure ceiling; 256^2 8-phase rejected on this geometry, R1-R4).
// EPI=0 (qkv): fused epilogue — q/k: RoPE via [row][col] LDS tile (stride 130);
//   v: acc -> transposed LDS tile [d][s] (stride 136) -> coalesced vt [B,H,D,S].
// EPI=1: plain fp32 store (out projection).
template <int EPI>
__global__ __launch_bounds__(256) void gemm_bt_k(const unsigned short* __restrict__ A,
                                                 const unsigned short* __restrict__ BT,
                                                 int K, int N,
                                                 float* __restrict__ outF,
                                                 unsigned short* __restrict__ oq,
                                                 unsigned short* __restrict__ ok,
                                                 unsigned short* __restrict__ ov) {
  __shared__ __align__(16) unsigned short smem[17408];
  unsigned short* lA = smem;
  unsigned short* lB = smem + 8192;
  const int tid = threadIdx.x;
  const int w = tid >> 6, lane = tid & 63;
  const int quad = lane >> 4, l16 = lane & 15;
  const int m0 = blockIdx.y * 128, n0 = blockIdx.x * 128;
  const int wm = (w >> 1) * 64, wn = (w & 1) * 64;
  f32x4 acc[4][4] = {};
  const int srow = tid >> 3;
  const int schunk = (tid & 7) ^ (srow & 7);
  const unsigned short* gA = A + (size_t)(m0 + srow) * K + schunk * 8;
  const unsigned short* gB = BT + (size_t)(n0 + srow) * K + schunk * 8;
  char* ldA = (char*)lA + tid * 16;
  char* ldB = (char*)lB + tid * 16;
  const size_t rskip = (size_t)32 * K;
  for (int k0 = 0; k0 < K; k0 += 64) {
#pragma unroll
    for (int j = 0; j < 4; j++) {
      g2l16(gA + k0 + j * rskip, ldA + j * 4096);
      g2l16(gB + k0 + j * rskip, ldB + j * 4096);
    }
    __syncthreads();
#pragma unroll
    for (int ks = 0; ks < 2; ks++) {
      bf16x8 af[4], bfv[4];
#pragma unroll
      for (int i = 0; i < 4; i++)
        af[i] = *(const bf16x8*)((const char*)lA + (size_t)(wm + i * 16 + l16) * 128 +
                                 ((size_t)((ks * 4 + quad) ^ (l16 & 7)) * 16));
#pragma unroll
      for (int j = 0; j < 4; j++)
        bfv[j] = *(const bf16x8*)((const char*)lB + (size_t)(wn + j * 16 + l16) * 128 +
                                  ((size_t)((ks * 4 + quad) ^ (l16 & 7)) * 16));
#pragma unroll
      for (int i = 0; i < 4; i++)
#pragma unroll
        for (int j = 0; j < 4; j++)
          acc[i][j] = __builtin_amdgcn_mfma_f32_16x16x32_bf16(af[i], bfv[j], acc[i][j], 0, 0, 0);
    }
    __syncthreads();
  }
  if (EPI == 0) {
    const int which = n0 >> 11;          // 0=q 1=k 2=v
    const int h = (n0 >> 7) & 15;        // tile spans exactly one head
    const int bi2 = m0 >> 11, s0 = m0 & 2047;   // whole tile is one batch
    if (which < 2) {
#pragma unroll
      for (int i = 0; i < 4; i++)
#pragma unroll
        for (int r = 0; r < 4; r++) {
          int row = wm + i * 16 + quad * 4 + r;
#pragma unroll
          for (int j = 0; j < 4; j++)
            smem[row * 130 + wn + j * 16 + l16] = f2bf(acc[i][j][r]);
        }
      __syncthreads();
      unsigned short* dst = (which == 0) ? oq : ok;
      const float scale = (which == 0) ? 0.08838834764831845f : 1.0f;
      const int d = tid & 63, tg = tid >> 6;
      const float fr = exp2f(-(float)d * (13.287712379549449f / 64.0f));
      const size_t hb = ((size_t)(bi2 * 16 + h) * 2048 + s0) * 128;
#pragma unroll
      for (int i = 0; i < 32; i++) {
        int r = i * 4 + tg;
        float a = bf2f(smem[r * 130 + d]);
        float bb = bf2f(smem[r * 130 + 64 + d]);
        float sn, cs;
        __sincosf((float)(s0 + r) * fr, &sn, &cs);
        dst[hb + (size_t)r * 128 + d]      = f2bf((a * cs - bb * sn) * scale);
        dst[hb + (size_t)r * 128 + 64 + d] = f2bf((bb * cs + a * sn) * scale);
      }
    } else {
#pragma unroll
      for (int i = 0; i < 4; i++)
#pragma unroll
        for (int j = 0; j < 4; j++) {
          int row = wm + i * 16 + quad * 4;       // s base (r=0..3 consecutive)
          int col = wn + j * 16 + l16;            // d
          ushort4 t4;
          t4.x = f2bf(acc[i][j][0]); t4.y = f2bf(acc[i][j][1]);
          t4.z = f2bf(acc[i][j][2]); t4.w = f2bf(acc[i][j][3]);
          *(ushort4*)&smem[col * 136 + row] = t4;
        }
      __syncthreads();
      const int sc = tid & 15, dbase = tid >> 4;
      const size_t vrb = ((size_t)(bi2 * 16 + h) * 128) * 2048 + s0;
#pragma unroll
      for (int v = 0; v < 8; v++) {
        int d = dbase + v * 16;
        uint4 val = *(const uint4*)&smem[d * 136 + sc * 8];
        *(uint4*)(ov + vrb + (size_t)d * 2048 + sc * 8) = val;
      }
    }
  } else {
#pragma unroll
    for (int i = 0; i < 4; i++)
#pragma unroll
      for (int r = 0; r < 4; r++) {
        size_t rowb = (size_t)(m0 + wm + i * 16 + quad * 4 + r) * N;
#pragma unroll
        for (int j = 0; j < 4; j++)
          outF[rowb + n0 + wn + j * 16 + l16] = acc[i][j][r];
      }
  }
}

// ---------------- flash attention v3: 2-phase double-buffered (T3 minimum) ----------------
// R6 vs R0: SAME 2 barriers/tile (R5's 4-barrier split regressed +22us), but K/V
// double-buffered in LDS: stage(kt+1) into buf^1 issued BEFORE compute(kt), one
// counted vmcnt(8) per tile (never 0 mid-loop; guide T3 minimum-2-phase recipe).
// HBM latency of stage(kt+1) hides under the full tile of compute(kt).
// Hazards: buf^1 was last read by compute(kt-1), finished before its end barrier
// (program-order before these stage issues) -> WAR safe. vmcnt(8) leaves exactly
// stage(kt+1)'s 8 ops in flight, drains stage(kt) (and the prologue Q loads on
// the first iteration) -> RAW safe; barrier publishes LDS to all waves.
// LDS: 2x16K (K) + 2x16K (V) + pbuf 16K = 81920 B -> 2 blocks/CU exactly.
// T5: setprio(1) around both MFMA clusters (m191: +4-7% attn).
__global__ __launch_bounds__(256, 2) void attn_k(const unsigned short* __restrict__ qb,
                                                 const unsigned short* __restrict__ kb,
                                                 const unsigned short* __restrict__ vt,
                                                 unsigned short* __restrict__ ob) {
  __shared__ __align__(16) unsigned short smem[32768];    // [2][8192] K | [2][8192] V
  __shared__ __align__(16) __bf16 pbuf[4][32 * 64];       // wave-private P (stride 64)
  const int tid = threadIdx.x;
  const int w = tid >> 6, lane = tid & 63;
  const int quad = lane >> 4, l16 = lane & 15;
  const int qt = (blockIdx.y < 16) ? (int)blockIdx.x : 15 - (int)blockIdx.x;
  const int bh = blockIdx.y;
  const int bi = bh >> 4, h = bh & 15;
  const int q0w = qt * 128 + w * 32;
  const unsigned short* qp = qb + (size_t)bh * 2048 * 128;
  const unsigned short* kp = kb + (size_t)bh * 2048 * 128;
  const unsigned short* vp = vt + (size_t)bh * 128 * 2048;
  __bf16* pw = pbuf[w];

  // Q fragments: 2 row-groups x 4 k-chunks, A-layout
  bf16x8 qf[2][4];
#pragma unroll
  for (int rg = 0; rg < 2; rg++) {
    const unsigned short* qr = qp + (size_t)(q0w + rg * 16 + l16) * 128 + quad * 8;
#pragma unroll
    for (int st = 0; st < 4; st++) qf[rg][st] = *(const bf16x8*)(qr + st * 32);
  }
  f32x4 o[2][8] = {};
  f32x4 lsum[2] = {};

  // staging index precompute (chunk l = j*256 + tid)
  const int krow = tid >> 4;                       // + j*16
  const int kcg = (tid & 15) ^ krow;
  const int vd = tid >> 3;                         // + j*32
  const int vsg = (tid & 7) ^ ((tid >> 3) & 7);

  const int nkt = 2 * qt + 2;                      // block-uniform
  const int myNkt = (q0w + 31) / 64 + 1;           // this wave's causal bound

  // prologue: stage K(0),V(0) into buf 0
#pragma unroll
  for (int j = 0; j < 4; j++) {
    g2l16(kp + (size_t)(j * 16 + krow) * 128 + kcg * 8, smem + tid * 8 + j * 2048);
    g2l16(vp + (size_t)(j * 32 + vd) * 2048 + vsg * 8, smem + 16384 + tid * 8 + j * 2048);
  }

  for (int kt = 0; kt < nkt; kt++) {
    const int cur = kt & 1;
    const unsigned short* lKc = smem + cur * 8192;
    const unsigned short* lVc = smem + 16384 + cur * 8192;
    if (kt + 1 < nkt) {
      unsigned short* kd = smem + (cur ^ 1) * 8192 + tid * 8;
      unsigned short* vdd = smem + 16384 + (cur ^ 1) * 8192 + tid * 8;
      const int kb0 = (kt + 1) * 64;
#pragma unroll
      for (int j = 0; j < 4; j++) {
        g2l16(kp + (size_t)(kb0 + j * 16 + krow) * 128 + kcg * 8, kd + j * 2048);
        g2l16(vp + (size_t)(j * 32 + vd) * 2048 + kb0 + vsg * 8, vdd + j * 2048);
      }
      asm volatile("s_waitcnt vmcnt(8)" ::: "memory");
    } else {
      asm volatile("s_waitcnt vmcnt(0)" ::: "memory");
    }
    BARX();
    if (kt < myNkt) {
      const int kt0 = kt * 64;
      // S = Q K^T (pre-scaled): 32 q-rows x 64 k-cols
      f32x4 sc[2][4] = {};
      __builtin_amdgcn_s_setprio(1);
#pragma unroll
      for (int ct = 0; ct < 4; ct++) {
        const int nrow = ct * 16 + l16;
#pragma unroll
        for (int st = 0; st < 4; st++) {
          bf16x8 kf = *(const bf16x8*)(lKc + ((size_t)nrow * 16 + ((st * 4 + quad) ^ l16)) * 8);
          sc[0][ct] = __builtin_amdgcn_mfma_f32_16x16x32_bf16(qf[0][st], kf, sc[0][ct], 0, 0, 0);
          sc[1][ct] = __builtin_amdgcn_mfma_f32_16x16x32_bf16(qf[1][st], kf, sc[1][ct], 0, 0, 0);
        }
      }
      __builtin_amdgcn_s_setprio(0);
      // exp (no max-subtract); causal mask only on the wave's LAST tile
      const bool needmask = (kt == myNkt - 1);
#pragma unroll
      for (int rg = 0; rg < 2; rg++)
#pragma unroll
        for (int ct = 0; ct < 4; ct++) {
          const int col = kt0 + ct * 16 + l16;
          const int rowb = q0w + rg * 16 + quad * 4;
#pragma unroll
          for (int r = 0; r < 4; r++) {
            float s = sc[rg][ct][r];
            if (needmask && col > rowb + r) s = -1e30f;
            float e = __expf(s);
            lsum[rg][r] += e;
            pw[(rg * 16 + quad * 4 + r) * 64 + ct * 16 + l16] = (__bf16)e;
          }
        }
      // P: C-layout -> LDS -> A-layout fragments
      bf16x8 pf[2][2];
#pragma unroll
      for (int rg = 0; rg < 2; rg++)
#pragma unroll
        for (int sb = 0; sb < 2; sb++)
          pf[rg][sb] = *(const bf16x8*)(pw + (rg * 16 + l16) * 64 + sb * 32 + quad * 8);
      // O += P @ V
      __builtin_amdgcn_s_setprio(1);
#pragma unroll
      for (int dt = 0; dt < 8; dt++) {
#pragma unroll
        for (int sb = 0; sb < 2; sb++) {
          bf16x8 vf = *(const bf16x8*)(lVc +
              ((size_t)(dt * 16 + l16) * 8 + ((sb * 4 + quad) ^ (l16 & 7))) * 8);
          o[0][dt] = __builtin_amdgcn_mfma_f32_16x16x32_bf16(pf[0][sb], vf, o[0][dt], 0, 0, 0);
          o[1][dt] = __builtin_amdgcn_mfma_f32_16x16x32_bf16(pf[1][sb], vf, o[1][dt], 0, 0, 0);
        }
      }
      __builtin_amdgcn_s_setprio(0);
    }
    BARX();
  }
  // reduce l across the 16 col-lanes (once per wave)
#pragma unroll
  for (int m = 1; m < 16; m <<= 1)
#pragma unroll
    for (int rg = 0; rg < 2; rg++)
#pragma unroll
      for (int r = 0; r < 4; r++)
        lsum[rg][r] += __shfl_xor(lsum[rg][r], m, 64);
  float inv[2][4];
#pragma unroll
  for (int rg = 0; rg < 2; rg++)
#pragma unroll
    for (int r = 0; r < 4; r++) inv[rg][r] = 1.0f / lsum[rg][r];
#pragma unroll
  for (int rg = 0; rg < 2; rg++)
#pragma unroll
    for (int dt = 0; dt < 8; dt++)
#pragma unroll
      for (int r = 0; r < 4; r++)
        ob[(size_t)(bi * 2048 + q0w + rg * 16 + quad * 4 + r) * 2048 + h * 128 + dt * 16 + l16] =
            f2bf(o[rg][dt][r] * inv[rg][r]);
}

extern "C" void kernel_launch(void* const* d_in, const int* in_sizes, int n_in,
                              void* d_out, int out_size, void* d_ws, size_t ws_size,
                              hipStream_t stream) {
  const float* x = (const float*)d_in[0];
  const float* wqkv = (const float*)d_in[1];
  const float* wout = (const float*)d_in[2];
  // d_in[3] = mask, unused (causal analytically)
  char* ws = (char*)d_ws;
  const size_t MiB = 1ull << 20;
  unsigned short* xb    = (unsigned short*)(ws + 0);         // [4096,2048] bf16   16 MiB
  unsigned short* wqkvT = (unsigned short*)(ws + 16 * MiB);  // [6144,2048] bf16   24 MiB
  unsigned short* woutT = (unsigned short*)(ws + 40 * MiB);  // [2048,2048] bf16    8 MiB
  unsigned short* qb    = (unsigned short*)(ws + 48 * MiB);  // [32,2048,128] bf16 16 MiB
  unsigned short* kb    = (unsigned short*)(ws + 64 * MiB);  // [32,2048,128]      16 MiB
  unsigned short* vtb   = (unsigned short*)(ws + 80 * MiB);  // [32,128,2048]      16 MiB
  unsigned short* attnb = (unsigned short*)(ws + 96 * MiB);  // [4096,2048] bf16   16 MiB
  float* outF = (float*)d_out;

  prep_k<<<12288, 256, 0, stream>>>(x, wqkv, wout, xb, wqkvT, woutT);
  gemm_bt_k<0><<<dim3(48, 32), 256, 0, stream>>>(xb, wqkvT, 2048, 6144, nullptr, qb, kb, vtb);
  attn_k<<<dim3(16, 32), 256, 0, stream>>>(qb, kb, vtb, attnb);
  gemm_bt_k<1><<<dim3(16, 32), 256, 0, stream>>>(attnb, woutT, 2048, 2048, outF,
                                                 nullptr, nullptr, nullptr);
}

// Round 7
// 387.901 us; speedup vs baseline: 1.0342x; 1.0041x over previous
//
#include <hip/hip_runtime.h>

typedef __attribute__((ext_vector_type(8))) __bf16 bf16x8;
typedef __attribute__((ext_vector_type(4))) float f32x4;

__device__ __forceinline__ unsigned short f2bf(float x) {
  union { float f; unsigned int u; } v; v.f = x;
  unsigned int r = v.u + 0x7fffu + ((v.u >> 16) & 1u);
  return (unsigned short)(r >> 16);
}
__device__ __forceinline__ float bf2f(unsigned short x) {
  union { unsigned int u; float f; } v; v.u = ((unsigned int)x) << 16;
  return v.f;
}
__device__ __forceinline__ void g2l16(const void* g, void* l) {
  __builtin_amdgcn_global_load_lds((const __attribute__((address_space(1))) void*)g,
                                   (__attribute__((address_space(3))) void*)l, 16, 0, 0);
}

#define BARX()                                  \
  do {                                          \
    asm volatile("" ::: "memory");              \
    __builtin_amdgcn_s_barrier();               \
    asm volatile("" ::: "memory");              \
  } while (0)

// ---------------- fused input prep ----------------
// blocks [0,8192):        x fp32 -> bf16            (float4 -> ushort4)
// blocks [8192,11264):    wqkv [2048,6144] -> transposed bf16 [6144,2048]
// blocks [11264,12288):   wout [2048,2048] -> transposed bf16 [2048,2048]
// Transpose legs vectorized (G13): float4 loads (16B/lane), ushort4 stores.
__global__ __launch_bounds__(256) void prep_k(const float* __restrict__ x,
                                              const float* __restrict__ wq,
                                              const float* __restrict__ wo,
                                              unsigned short* __restrict__ xb,
                                              unsigned short* __restrict__ wqT,
                                              unsigned short* __restrict__ woT) {
  __shared__ unsigned short t[64][65];
  const int b = blockIdx.x;
  if (b < 8192) {
    int i = b * 256 + threadIdx.x;
    float4 v = ((const float4*)x)[i];
    ushort4 o;
    o.x = f2bf(v.x); o.y = f2bf(v.y); o.z = f2bf(v.z); o.w = f2bf(v.w);
    ((ushort4*)xb)[i] = o;
    return;
  }
  const float* in; unsigned short* out; int C, c0, r0;
  const int R = 2048;
  if (b < 11264) { int bb = b - 8192;  in = wq; out = wqT; C = 6144; c0 = (bb % 96) * 64; r0 = (bb / 96) * 64; }
  else           { int bb = b - 11264; in = wo; out = woT; C = 2048; c0 = (bb & 31) * 64; r0 = (bb >> 5) * 64; }
  const int tx16 = threadIdx.x & 15, rr4 = threadIdx.x >> 4;   // 16 lanes x 16 rows
#pragma unroll
  for (int p = 0; p < 4; p++) {
    const int r = p * 16 + rr4;
    float4 v = *(const float4*)&in[(size_t)(r0 + r) * C + c0 + tx16 * 4];
    t[r][tx16 * 4 + 0] = f2bf(v.x);
    t[r][tx16 * 4 + 1] = f2bf(v.y);
    t[r][tx16 * 4 + 2] = f2bf(v.z);
    t[r][tx16 * 4 + 3] = f2bf(v.w);
  }
  __syncthreads();
#pragma unroll
  for (int p = 0; p < 4; p++) {
    const int c = p * 16 + rr4;
    ushort4 o4;
    o4.x = t[tx16 * 4 + 0][c];
    o4.y = t[tx16 * 4 + 1][c];
    o4.z = t[tx16 * 4 + 2][c];
    o4.w = t[tx16 * 4 + 3][c];
    *(ushort4*)&out[(size_t)(c0 + c) * R + r0 + tx16 * 4] = o4;
  }
}

// ---------------- GEMM: C[M,N] = A[M,K](bf16) @ BT[N,K](bf16)^T ----------------
// R0 kernel verbatim (measured 123-125 us QKV, VGPR 84, no spill, ~837 TF —
// at the m97-structure ceiling for this geometry; 256^2 8-phase rejected R1-R4).
// EPI=0 (qkv): fused epilogue — q/k: RoPE via [row][col] LDS tile (stride 130);
//   v: acc -> transposed LDS tile [d][s] (stride 136) -> coalesced vt [B,H,D,S].
// EPI=1: plain fp32 store (out projection).
template <int EPI>
__global__ __launch_bounds__(256) void gemm_bt_k(const unsigned short* __restrict__ A,
                                                 const unsigned short* __restrict__ BT,
                                                 int K, int N,
                                                 float* __restrict__ outF,
                                                 unsigned short* __restrict__ oq,
                                                 unsigned short* __restrict__ ok,
                                                 unsigned short* __restrict__ ov) {
  __shared__ __align__(16) unsigned short smem[17408];
  unsigned short* lA = smem;
  unsigned short* lB = smem + 8192;
  const int tid = threadIdx.x;
  const int w = tid >> 6, lane = tid & 63;
  const int quad = lane >> 4, l16 = lane & 15;
  const int m0 = blockIdx.y * 128, n0 = blockIdx.x * 128;
  const int wm = (w >> 1) * 64, wn = (w & 1) * 64;
  f32x4 acc[4][4] = {};
  const int srow = tid >> 3;
  const int schunk = (tid & 7) ^ (srow & 7);
  const unsigned short* gA = A + (size_t)(m0 + srow) * K + schunk * 8;
  const unsigned short* gB = BT + (size_t)(n0 + srow) * K + schunk * 8;
  char* ldA = (char*)lA + tid * 16;
  char* ldB = (char*)lB + tid * 16;
  const size_t rskip = (size_t)32 * K;
  for (int k0 = 0; k0 < K; k0 += 64) {
#pragma unroll
    for (int j = 0; j < 4; j++) {
      g2l16(gA + k0 + j * rskip, ldA + j * 4096);
      g2l16(gB + k0 + j * rskip, ldB + j * 4096);
    }
    __syncthreads();
#pragma unroll
    for (int ks = 0; ks < 2; ks++) {
      bf16x8 af[4], bfv[4];
#pragma unroll
      for (int i = 0; i < 4; i++)
        af[i] = *(const bf16x8*)((const char*)lA + (size_t)(wm + i * 16 + l16) * 128 +
                                 ((size_t)((ks * 4 + quad) ^ (l16 & 7)) * 16));
#pragma unroll
      for (int j = 0; j < 4; j++)
        bfv[j] = *(const bf16x8*)((const char*)lB + (size_t)(wn + j * 16 + l16) * 128 +
                                  ((size_t)((ks * 4 + quad) ^ (l16 & 7)) * 16));
#pragma unroll
      for (int i = 0; i < 4; i++)
#pragma unroll
        for (int j = 0; j < 4; j++)
          acc[i][j] = __builtin_amdgcn_mfma_f32_16x16x32_bf16(af[i], bfv[j], acc[i][j], 0, 0, 0);
    }
    __syncthreads();
  }
  if (EPI == 0) {
    const int which = n0 >> 11;          // 0=q 1=k 2=v
    const int h = (n0 >> 7) & 15;        // tile spans exactly one head
    const int bi2 = m0 >> 11, s0 = m0 & 2047;   // whole tile is one batch
    if (which < 2) {
#pragma unroll
      for (int i = 0; i < 4; i++)
#pragma unroll
        for (int r = 0; r < 4; r++) {
          int row = wm + i * 16 + quad * 4 + r;
#pragma unroll
          for (int j = 0; j < 4; j++)
            smem[row * 130 + wn + j * 16 + l16] = f2bf(acc[i][j][r]);
        }
      __syncthreads();
      unsigned short* dst = (which == 0) ? oq : ok;
      const float scale = (which == 0) ? 0.08838834764831845f : 1.0f;
      const int d = tid & 63, tg = tid >> 6;
      const float fr = exp2f(-(float)d * (13.287712379549449f / 64.0f));
      const size_t hb = ((size_t)(bi2 * 16 + h) * 2048 + s0) * 128;
#pragma unroll
      for (int i = 0; i < 32; i++) {
        int r = i * 4 + tg;
        float a = bf2f(smem[r * 130 + d]);
        float bb = bf2f(smem[r * 130 + 64 + d]);
        float sn, cs;
        __sincosf((float)(s0 + r) * fr, &sn, &cs);
        dst[hb + (size_t)r * 128 + d]      = f2bf((a * cs - bb * sn) * scale);
        dst[hb + (size_t)r * 128 + 64 + d] = f2bf((bb * cs + a * sn) * scale);
      }
    } else {
#pragma unroll
      for (int i = 0; i < 4; i++)
#pragma unroll
        for (int j = 0; j < 4; j++) {
          int row = wm + i * 16 + quad * 4;       // s base (r=0..3 consecutive)
          int col = wn + j * 16 + l16;            // d
          ushort4 t4;
          t4.x = f2bf(acc[i][j][0]); t4.y = f2bf(acc[i][j][1]);
          t4.z = f2bf(acc[i][j][2]); t4.w = f2bf(acc[i][j][3]);
          *(ushort4*)&smem[col * 136 + row] = t4;
        }
      __syncthreads();
      const int sc = tid & 15, dbase = tid >> 4;
      const size_t vrb = ((size_t)(bi2 * 16 + h) * 128) * 2048 + s0;
#pragma unroll
      for (int v = 0; v < 8; v++) {
        int d = dbase + v * 16;
        uint4 val = *(const uint4*)&smem[d * 136 + sc * 8];
        *(uint4*)(ov + vrb + (size_t)d * 2048 + sc * 8) = val;
      }
    }
  } else {
#pragma unroll
    for (int i = 0; i < 4; i++)
#pragma unroll
      for (int r = 0; r < 4; r++) {
        size_t rowb = (size_t)(m0 + wm + i * 16 + quad * 4 + r) * N;
#pragma unroll
        for (int j = 0; j < 4; j++)
          outF[rowb + n0 + wn + j * 16 + l16] = acc[i][j][r];
      }
  }
}

// ---------------- flash attention v4: R0 + K-prefetch only ----------------
// R7: SINGLE change vs R0's proven attn (R5/R6 post-mortem: 4-barrier split and
// pbuf stride 72->64 both regressed — stride 64 puts P-writes 8-way / P-reads
// 16-way on banks; setprio hurts lockstep blocks per m190). Here: pbuf stride 72
// and compute bodies byte-identical to R0; K double-buffered, K(kt+1) issued at
// loop-top into lK[cur^1] (WAR-safe: after prev tile's end barrier), counted
// vmcnt(4) keeps it in flight across the wait (drains exactly K(kt)+V(kt)).
// V single-buffered, staged after the post-compute barrier (as R0).
// FIFO ledger per wave at the wait: outstanding <= {K(kt),V(kt),K(kt+1)} = 12
// -> vmcnt(4) leaves only K(kt+1); last tile vmcnt(0). 2 barriers/tile.
// LDS: 2x16K (lK) + 16K (lV) + 18432 (pbuf) = 67584 B -> 2 blocks/CU.
__global__ __launch_bounds__(256, 2) void attn_k(const unsigned short* __restrict__ qb,
                                                 const unsigned short* __restrict__ kb,
                                                 const unsigned short* __restrict__ vt,
                                                 unsigned short* __restrict__ ob) {
  __shared__ __align__(16) unsigned short lK[2][8192];    // chunk l = row*16 + (cg^row&15)
  __shared__ __align__(16) unsigned short lV[8192];       // chunk l = d*8 + (sg^d&7)
  __shared__ __align__(16) __bf16 pbuf[4][32 * 72];       // wave-private P (stride 72)
  const int tid = threadIdx.x;
  const int w = tid >> 6, lane = tid & 63;
  const int quad = lane >> 4, l16 = lane & 15;
  // complementary qt pairing for causal load balance
  const int qt = (blockIdx.y < 16) ? (int)blockIdx.x : 15 - (int)blockIdx.x;
  const int bh = blockIdx.y;
  const int bi = bh >> 4, h = bh & 15;
  const int q0w = qt * 128 + w * 32;
  const unsigned short* qp = qb + (size_t)bh * 2048 * 128;
  const unsigned short* kp = kb + (size_t)bh * 2048 * 128;
  const unsigned short* vp = vt + (size_t)bh * 128 * 2048;
  __bf16* pw = pbuf[w];

  // Q fragments: 2 row-groups x 4 k-chunks, A-layout
  bf16x8 qf[2][4];
#pragma unroll
  for (int rg = 0; rg < 2; rg++) {
    const unsigned short* qr = qp + (size_t)(q0w + rg * 16 + l16) * 128 + quad * 8;
#pragma unroll
    for (int st = 0; st < 4; st++) qf[rg][st] = *(const bf16x8*)(qr + st * 32);
  }
  f32x4 o[2][8] = {};
  f32x4 lsum[2] = {};

  // staging index precompute (chunk l = j*256 + tid)
  const int krow = tid >> 4;                       // + j*16
  const int kcg = (tid & 15) ^ krow;               // row&15 == krow (krow<16)
  const int vd = tid >> 3;                         // + j*32
  const int vsg = (tid & 7) ^ ((tid >> 3) & 7);

  const int nkt = 2 * qt + 2;                      // block-uniform (barriers)
  const int myNkt = (q0w + 31) / 64 + 1;           // this wave's causal bound

  // prologue: stage K(0) -> lK[0], V(0) -> lV
#pragma unroll
  for (int j = 0; j < 4; j++) {
    g2l16(kp + (size_t)(j * 16 + krow) * 128 + kcg * 8, lK[0] + tid * 8 + j * 2048);
    g2l16(vp + (size_t)(j * 32 + vd) * 2048 + vsg * 8, lV + tid * 8 + j * 2048);
  }

  for (int kt = 0; kt < nkt; kt++) {
    const int cur = kt & 1;
    if (kt + 1 < nkt) {
      const int kb0 = (kt + 1) * 64;
#pragma unroll
      for (int j = 0; j < 4; j++)
        g2l16(kp + (size_t)(kb0 + j * 16 + krow) * 128 + kcg * 8,
              lK[cur ^ 1] + tid * 8 + j * 2048);
      asm volatile("s_waitcnt vmcnt(4)" ::: "memory");
    } else {
      asm volatile("s_waitcnt vmcnt(0)" ::: "memory");
    }
    BARX();
    if (kt < myNkt) {
      const int kt0 = kt * 64;
      const unsigned short* lKc = lK[cur];
      // S = Q K^T (pre-scaled): 32 q-rows x 64 k-cols
      f32x4 sc[2][4] = {};
#pragma unroll
      for (int ct = 0; ct < 4; ct++) {
        const int nrow = ct * 16 + l16;
#pragma unroll
        for (int st = 0; st < 4; st++) {
          bf16x8 kf = *(const bf16x8*)(lKc + ((size_t)nrow * 16 + ((st * 4 + quad) ^ l16)) * 8);
          sc[0][ct] = __builtin_amdgcn_mfma_f32_16x16x32_bf16(qf[0][st], kf, sc[0][ct], 0, 0, 0);
          sc[1][ct] = __builtin_amdgcn_mfma_f32_16x16x32_bf16(qf[1][st], kf, sc[1][ct], 0, 0, 0);
        }
      }
      // exp (no max-subtract); causal mask only on the wave's LAST tile
      const bool needmask = (kt == myNkt - 1);
#pragma unroll
      for (int rg = 0; rg < 2; rg++)
#pragma unroll
        for (int ct = 0; ct < 4; ct++) {
          const int col = kt0 + ct * 16 + l16;
          const int rowb = q0w + rg * 16 + quad * 4;
#pragma unroll
          for (int r = 0; r < 4; r++) {
            float s = sc[rg][ct][r];
            if (needmask && col > rowb + r) s = -1e30f;
            float e = __expf(s);
            lsum[rg][r] += e;
            pw[(rg * 16 + quad * 4 + r) * 72 + ct * 16 + l16] = (__bf16)e;
          }
        }
      // P: C-layout -> LDS -> A-layout fragments
      bf16x8 pf[2][2];
#pragma unroll
      for (int rg = 0; rg < 2; rg++)
#pragma unroll
        for (int sb = 0; sb < 2; sb++)
          pf[rg][sb] = *(const bf16x8*)(pw + (rg * 16 + l16) * 72 + sb * 32 + quad * 8);
      // O += P @ V
#pragma unroll
      for (int dt = 0; dt < 8; dt++) {
#pragma unroll
        for (int sb = 0; sb < 2; sb++) {
          bf16x8 vf = *(const bf16x8*)(lV +
              ((size_t)(dt * 16 + l16) * 8 + ((sb * 4 + quad) ^ (l16 & 7))) * 8);
          o[0][dt] = __builtin_amdgcn_mfma_f32_16x16x32_bf16(pf[0][sb], vf, o[0][dt], 0, 0, 0);
          o[1][dt] = __builtin_amdgcn_mfma_f32_16x16x32_bf16(pf[1][sb], vf, o[1][dt], 0, 0, 0);
        }
      }
    }
    BARX();   // all PV reads of lV complete across the block
    if (kt + 1 < nkt) {
      const int kb0 = (kt + 1) * 64;
#pragma unroll
      for (int j = 0; j < 4; j++)
        g2l16(vp + (size_t)(j * 32 + vd) * 2048 + kb0 + vsg * 8, lV + tid * 8 + j * 2048);
    }
  }
  // reduce l across the 16 col-lanes (once per wave)
#pragma unroll
  for (int m = 1; m < 16; m <<= 1)
#pragma unroll
    for (int rg = 0; rg < 2; rg++)
#pragma unroll
      for (int r = 0; r < 4; r++)
        lsum[rg][r] += __shfl_xor(lsum[rg][r], m, 64);
  float inv[2][4];
#pragma unroll
  for (int rg = 0; rg < 2; rg++)
#pragma unroll
    for (int r = 0; r < 4; r++) inv[rg][r] = 1.0f / lsum[rg][r];
#pragma unroll
  for (int rg = 0; rg < 2; rg++)
#pragma unroll
    for (int dt = 0; dt < 8; dt++)
#pragma unroll
      for (int r = 0; r < 4; r++)
        ob[(size_t)(bi * 2048 + q0w + rg * 16 + quad * 4 + r) * 2048 + h * 128 + dt * 16 + l16] =
            f2bf(o[rg][dt][r] * inv[rg][r]);
}

extern "C" void kernel_launch(void* const* d_in, const int* in_sizes, int n_in,
                              void* d_out, int out_size, void* d_ws, size_t ws_size,
                              hipStream_t stream) {
  const float* x = (const float*)d_in[0];
  const float* wqkv = (const float*)d_in[1];
  const float* wout = (const float*)d_in[2];
  // d_in[3] = mask, unused (causal analytically)
  char* ws = (char*)d_ws;
  const size_t MiB = 1ull << 20;
  unsigned short* xb    = (unsigned short*)(ws + 0);         // [4096,2048] bf16   16 MiB
  unsigned short* wqkvT = (unsigned short*)(ws + 16 * MiB);  // [6144,2048] bf16   24 MiB
  unsigned short* woutT = (unsigned short*)(ws + 40 * MiB);  // [2048,2048] bf16    8 MiB
  unsigned short* qb    = (unsigned short*)(ws + 48 * MiB);  // [32,2048,128] bf16 16 MiB
  unsigned short* kb    = (unsigned short*)(ws + 64 * MiB);  // [32,2048,128]      16 MiB
  unsigned short* vtb   = (unsigned short*)(ws + 80 * MiB);  // [32,128,2048]      16 MiB
  unsigned short* attnb = (unsigned short*)(ws + 96 * MiB);  // [4096,2048] bf16   16 MiB
  float* outF = (float*)d_out;

  prep_k<<<12288, 256, 0, stream>>>(x, wqkv, wout, xb, wqkvT, woutT);
  gemm_bt_k<0><<<dim3(48, 32), 256, 0, stream>>>(xb, wqkvT, 2048, 6144, nullptr, qb, kb, vtb);
  attn_k<<<dim3(16, 32), 256, 0, stream>>>(qb, kb, vtb, attnb);
  gemm_bt_k<1><<<dim3(16, 32), 256, 0, stream>>>(attnb, woutT, 2048, 2048, outF,
                                                 nullptr, nullptr, nullptr);
}

// Round 9
// 386.306 us; speedup vs baseline: 1.0385x; 1.0041x over previous
//
#include <hip/hip_runtime.h>

typedef __attribute__((ext_vector_type(8))) __bf16 bf16x8;
typedef __attribute__((ext_vector_type(4))) float f32x4;

__device__ __forceinline__ unsigned short f2bf(float x) {
  union { float f; unsigned int u; } v; v.f = x;
  unsigned int r = v.u + 0x7fffu + ((v.u >> 16) & 1u);
  return (unsigned short)(r >> 16);
}
__device__ __forceinline__ float bf2f(unsigned short x) {
  union { unsigned int u; float f; } v; v.u = ((unsigned int)x) << 16;
  return v.f;
}
__device__ __forceinline__ void g2l16(const void* g, void* l) {
  __builtin_amdgcn_global_load_lds((const __attribute__((address_space(1))) void*)g,
                                   (__attribute__((address_space(3))) void*)l, 16, 0, 0);
}

// ---------------- fused input prep (R0 verbatim) ----------------
// blocks [0,8192):        x fp32 -> bf16            (4 elems/thread)
// blocks [8192,11264):    wqkv [2048,6144] -> transposed bf16 [6144,2048]
// blocks [11264,12288):   wout [2048,2048] -> transposed bf16 [2048,2048]
__global__ __launch_bounds__(256) void prep_k(const float* __restrict__ x,
                                              const float* __restrict__ wq,
                                              const float* __restrict__ wo,
                                              unsigned short* __restrict__ xb,
                                              unsigned short* __restrict__ wqT,
                                              unsigned short* __restrict__ woT) {
  __shared__ unsigned short t[64][65];
  const int b = blockIdx.x;
  if (b < 8192) {
    int i = b * 256 + threadIdx.x;
    float4 v = ((const float4*)x)[i];
    ushort4 o;
    o.x = f2bf(v.x); o.y = f2bf(v.y); o.z = f2bf(v.z); o.w = f2bf(v.w);
    ((ushort4*)xb)[i] = o;
    return;
  }
  const float* in; unsigned short* out; int C, c0, r0;
  const int R = 2048;
  if (b < 11264) { int bb = b - 8192;  in = wq; out = wqT; C = 6144; c0 = (bb % 96) * 64; r0 = (bb / 96) * 64; }
  else           { int bb = b - 11264; in = wo; out = woT; C = 2048; c0 = (bb & 31) * 64; r0 = (bb >> 5) * 64; }
  const int tx = threadIdx.x & 63, tg = threadIdx.x >> 6;
#pragma unroll
  for (int i = 0; i < 16; i++) {
    int r = i * 4 + tg;
    t[r][tx] = f2bf(in[(size_t)(r0 + r) * C + c0 + tx]);
  }
  __syncthreads();
#pragma unroll
  for (int i = 0; i < 16; i++) {
    int c = i * 4 + tg;
    out[(size_t)(c0 + c) * R + r0 + tx] = t[tx][c];
  }
}

// ---------------- GEMM: C[M,N] = A[M,K](bf16) @ BT[N,K](bf16)^T (R0 verbatim) ----------------
// 128x128 tile, BK=64, XOR-swizzled conflict-free LDS. Measured 123-125 us QKV,
// VGPR 84, no spill, ~837 TF — at the m97-structure ceiling for this geometry
// (256^2 8-phase rejected on this geometry: R1-R4 — 0.75 dispatch tail + lockstep).
// EPI=0 (qkv): fused epilogue — q/k: RoPE via [row][col] LDS tile (stride 130);
//   v: acc -> transposed LDS tile [d][s] (stride 136) -> coalesced vt [B,H,D,S].
// EPI=1: plain fp32 store (out projection).
template <int EPI>
__global__ __launch_bounds__(256) void gemm_bt_k(const unsigned short* __restrict__ A,
                                                 const unsigned short* __restrict__ BT,
                                                 int K, int N,
                                                 float* __restrict__ outF,
                                                 unsigned short* __restrict__ oq,
                                                 unsigned short* __restrict__ ok,
                                                 unsigned short* __restrict__ ov) {
  __shared__ __align__(16) unsigned short smem[17408];
  unsigned short* lA = smem;
  unsigned short* lB = smem + 8192;
  const int tid = threadIdx.x;
  const int w = tid >> 6, lane = tid & 63;
  const int quad = lane >> 4, l16 = lane & 15;
  const int m0 = blockIdx.y * 128, n0 = blockIdx.x * 128;
  const int wm = (w >> 1) * 64, wn = (w & 1) * 64;
  f32x4 acc[4][4] = {};
  const int srow = tid >> 3;
  const int schunk = (tid & 7) ^ (srow & 7);
  const unsigned short* gA = A + (size_t)(m0 + srow) * K + schunk * 8;
  const unsigned short* gB = BT + (size_t)(n0 + srow) * K + schunk * 8;
  char* ldA = (char*)lA + tid * 16;
  char* ldB = (char*)lB + tid * 16;
  const size_t rskip = (size_t)32 * K;
  for (int k0 = 0; k0 < K; k0 += 64) {
#pragma unroll
    for (int j = 0; j < 4; j++) {
      g2l16(gA + k0 + j * rskip, ldA + j * 4096);
      g2l16(gB + k0 + j * rskip, ldB + j * 4096);
    }
    __syncthreads();
#pragma unroll
    for (int ks = 0; ks < 2; ks++) {
      bf16x8 af[4], bfv[4];
#pragma unroll
      for (int i = 0; i < 4; i++)
        af[i] = *(const bf16x8*)((const char*)lA + (size_t)(wm + i * 16 + l16) * 128 +
                                 ((size_t)((ks * 4 + quad) ^ (l16 & 7)) * 16));
#pragma unroll
      for (int j = 0; j < 4; j++)
        bfv[j] = *(const bf16x8*)((const char*)lB + (size_t)(wn + j * 16 + l16) * 128 +
                                  ((size_t)((ks * 4 + quad) ^ (l16 & 7)) * 16));
#pragma unroll
      for (int i = 0; i < 4; i++)
#pragma unroll
        for (int j = 0; j < 4; j++)
          acc[i][j] = __builtin_amdgcn_mfma_f32_16x16x32_bf16(af[i], bfv[j], acc[i][j], 0, 0, 0);
    }
    __syncthreads();
  }
  if (EPI == 0) {
    const int which = n0 >> 11;          // 0=q 1=k 2=v
    const int h = (n0 >> 7) & 15;        // tile spans exactly one head
    const int bi2 = m0 >> 11, s0 = m0 & 2047;   // whole tile is one batch
    if (which < 2) {
#pragma unroll
      for (int i = 0; i < 4; i++)
#pragma unroll
        for (int r = 0; r < 4; r++) {
          int row = wm + i * 16 + quad * 4 + r;
#pragma unroll
          for (int j = 0; j < 4; j++)
            smem[row * 130 + wn + j * 16 + l16] = f2bf(acc[i][j][r]);
        }
      __syncthreads();
      unsigned short* dst = (which == 0) ? oq : ok;
      const float scale = (which == 0) ? 0.08838834764831845f : 1.0f;
      const int d = tid & 63, tg = tid >> 6;
      const float fr = exp2f(-(float)d * (13.287712379549449f / 64.0f));
      const size_t hb = ((size_t)(bi2 * 16 + h) * 2048 + s0) * 128;
#pragma unroll
      for (int i = 0; i < 32; i++) {
        int r = i * 4 + tg;
        float a = bf2f(smem[r * 130 + d]);
        float bb = bf2f(smem[r * 130 + 64 + d]);
        float sn, cs;
        __sincosf((float)(s0 + r) * fr, &sn, &cs);
        dst[hb + (size_t)r * 128 + d]      = f2bf((a * cs - bb * sn) * scale);
        dst[hb + (size_t)r * 128 + 64 + d] = f2bf((bb * cs + a * sn) * scale);
      }
    } else {
#pragma unroll
      for (int i = 0; i < 4; i++)
#pragma unroll
        for (int j = 0; j < 4; j++) {
          int row = wm + i * 16 + quad * 4;       // s base (r=0..3 consecutive)
          int col = wn + j * 16 + l16;            // d
          ushort4 t4;
          t4.x = f2bf(acc[i][j][0]); t4.y = f2bf(acc[i][j][1]);
          t4.z = f2bf(acc[i][j][2]); t4.w = f2bf(acc[i][j][3]);
          *(ushort4*)&smem[col * 136 + row] = t4;
        }
      __syncthreads();
      const int sc = tid & 15, dbase = tid >> 4;
      const size_t vrb = ((size_t)(bi2 * 16 + h) * 128) * 2048 + s0;
#pragma unroll
      for (int v = 0; v < 8; v++) {
        int d = dbase + v * 16;
        uint4 val = *(const uint4*)&smem[d * 136 + sc * 8];
        *(uint4*)(ov + vrb + (size_t)d * 2048 + sc * 8) = val;
      }
    }
  } else {
#pragma unroll
    for (int i = 0; i < 4; i++)
#pragma unroll
      for (int r = 0; r < 4; r++) {
        size_t rowb = (size_t)(m0 + wm + i * 16 + quad * 4 + r) * N;
#pragma unroll
        for (int j = 0; j < 4; j++)
          outF[rowb + n0 + wn + j * 16 + l16] = acc[i][j][r];
      }
  }
}

// ---------------- flash attention (R0 body; R9: XCD-clustered mapping, FIXED decode) ----------------
// R8 bug: half=(f>>6)&1 overlapped qtRaw's top bit (bits 3-6) -> qt in 8..15 never
// produced (half the q-tiles unwritten; duplicates for 0..7). R9: half=(f>>8)&1 —
// bit 8 is disjoint from qtRaw (3-6) and bh-group (7). Bijection verified by range:
//   f in [0,128): grp0 qt 0..15 | [128,256): grp1 qt 0..15
//   [256,384): grp2 qt 15..0    | [384,512): grp3 qt 15..0   — all 512 (bh,qt) once.
// Mechanism (T1): dispatch round-robins f mod 8 across XCDs -> all 16 q-tiles of a
// bh land on ONE XCD; each XCD re-reads only its 4 bh's K/V (4 MB = L2-sized), so
// the ~8x HBM KV amplification (278 MB) collapses to L2 hits. Pairing: CU slot c
// gets r=c and r=c+32 -> qt = c&15 and 15-(c&15) -> 34 tiles per CU pair, balanced.
// Kernel body byte-identical to R0's proven attn (R5-R7: wait-shuffling null-to-
// negative; pbuf stride 72 load-bearing for bank spread).
__global__ __launch_bounds__(256, 2) void attn_k(const unsigned short* __restrict__ qb,
                                                 const unsigned short* __restrict__ kb,
                                                 const unsigned short* __restrict__ vt,
                                                 unsigned short* __restrict__ ob) {
  __shared__ __align__(16) unsigned short lK[64 * 128];   // chunk l = row*16 + (cg^row&15)
  __shared__ __align__(16) unsigned short lV[128 * 64];   // chunk l = d*8 + (sg^d&7)
  __shared__ __align__(16) __bf16 pbuf[4][32 * 72];       // wave-private P (stride 72)
  const int tid = threadIdx.x;
  const int w = tid >> 6, lane = tid & 63;
  const int quad = lane >> 4, l16 = lane & 15;
  // XCD-clustered decode + complementary causal pairing (bits: 0-2 xcd, 3-6 qtRaw,
  // 7 bh-group-low, 8 half/bh-group-high — all disjoint)
  const int f = (int)blockIdx.x;
  const int xcd = f & 7;
  const int qtRaw = (f >> 3) & 15;
  const int half = (f >> 8) & 1;          // FIXED (was bit 6 = qtRaw's top bit)
  const int bh = xcd + 8 * (f >> 7);      // bh mod 8 == xcd (KV L2-resident per XCD)
  const int qt = half ? 15 - qtRaw : qtRaw;
  const int bi = bh >> 4, h = bh & 15;
  const int q0w = qt * 128 + w * 32;
  const unsigned short* qp = qb + (size_t)bh * 2048 * 128;
  const unsigned short* kp = kb + (size_t)bh * 2048 * 128;
  const unsigned short* vp = vt + (size_t)bh * 128 * 2048;
  __bf16* pw = pbuf[w];

  // Q fragments: 2 row-groups x 4 k-chunks, A-layout
  bf16x8 qf[2][4];
#pragma unroll
  for (int rg = 0; rg < 2; rg++) {
    const unsigned short* qr = qp + (size_t)(q0w + rg * 16 + l16) * 128 + quad * 8;
#pragma unroll
    for (int st = 0; st < 4; st++) qf[rg][st] = *(const bf16x8*)(qr + st * 32);
  }
  f32x4 o[2][8] = {};
  f32x4 lsum[2] = {};

  // staging index precompute (chunk l = j*256 + tid)
  const int krow = tid >> 4;                       // + j*16
  const int kcg = (tid & 15) ^ krow;               // row&15 == krow (krow<16)
  const int vd = tid >> 3;                         // + j*32
  const int vsg = (tid & 7) ^ ((tid >> 3) & 7);
  unsigned short* lKdst = lK + (size_t)tid * 8;    // + j*2048 shorts
  unsigned short* lVdst = lV + (size_t)tid * 8;

  const int nkt = 2 * qt + 2;                      // block-uniform (barriers)
  const int myNkt = (q0w + 31) / 64 + 1;           // this wave's causal bound
  for (int kt = 0; kt < nkt; kt++) {
    const int kt0 = kt * 64;
#pragma unroll
    for (int j = 0; j < 4; j++) {
      g2l16(kp + (size_t)(kt0 + j * 16 + krow) * 128 + kcg * 8, lKdst + j * 2048);
      g2l16(vp + (size_t)(j * 32 + vd) * 2048 + kt0 + vsg * 8, lVdst + j * 2048);
    }
    __syncthreads();
    if (kt < myNkt) {
      // S = Q K^T (pre-scaled): 32 q-rows x 64 k-cols
      f32x4 sc[2][4] = {};
#pragma unroll
      for (int ct = 0; ct < 4; ct++) {
        const int nrow = ct * 16 + l16;
#pragma unroll
        for (int st = 0; st < 4; st++) {
          bf16x8 kf = *(const bf16x8*)(lK + ((size_t)nrow * 16 + ((st * 4 + quad) ^ l16)) * 8);
          sc[0][ct] = __builtin_amdgcn_mfma_f32_16x16x32_bf16(qf[0][st], kf, sc[0][ct], 0, 0, 0);
          sc[1][ct] = __builtin_amdgcn_mfma_f32_16x16x32_bf16(qf[1][st], kf, sc[1][ct], 0, 0, 0);
        }
      }
      // exp (no max-subtract); causal mask only on the wave's LAST tile
      const bool needmask = (kt == myNkt - 1);
#pragma unroll
      for (int rg = 0; rg < 2; rg++)
#pragma unroll
        for (int ct = 0; ct < 4; ct++) {
          const int col = kt0 + ct * 16 + l16;
          const int rowb = q0w + rg * 16 + quad * 4;
#pragma unroll
          for (int r = 0; r < 4; r++) {
            float s = sc[rg][ct][r];
            if (needmask && col > rowb + r) s = -1e30f;
            float e = __expf(s);
            lsum[rg][r] += e;
            pw[(rg * 16 + quad * 4 + r) * 72 + ct * 16 + l16] = (__bf16)e;
          }
        }
      // P: C-layout -> LDS -> A-layout fragments
      bf16x8 pf[2][2];
#pragma unroll
      for (int rg = 0; rg < 2; rg++)
#pragma unroll
        for (int sb = 0; sb < 2; sb++)
          pf[rg][sb] = *(const bf16x8*)(pw + (rg * 16 + l16) * 72 + sb * 32 + quad * 8);
      // O += P @ V
#pragma unroll
      for (int dt = 0; dt < 8; dt++) {
#pragma unroll
        for (int sb = 0; sb < 2; sb++) {
          bf16x8 vf = *(const bf16x8*)(lV +
              ((size_t)(dt * 16 + l16) * 8 + ((sb * 4 + quad) ^ (l16 & 7))) * 8);
          o[0][dt] = __builtin_amdgcn_mfma_f32_16x16x32_bf16(pf[0][sb], vf, o[0][dt], 0, 0, 0);
          o[1][dt] = __builtin_amdgcn_mfma_f32_16x16x32_bf16(pf[1][sb], vf, o[1][dt], 0, 0, 0);
        }
      }
    }
    __syncthreads();
  }
  // reduce l across the 16 col-lanes (once per wave)
#pragma unroll
  for (int m = 1; m < 16; m <<= 1)
#pragma unroll
    for (int rg = 0; rg < 2; rg++)
#pragma unroll
      for (int r = 0; r < 4; r++)
        lsum[rg][r] += __shfl_xor(lsum[rg][r], m, 64);
  float inv[2][4];
#pragma unroll
  for (int rg = 0; rg < 2; rg++)
#pragma unroll
    for (int r = 0; r < 4; r++) inv[rg][r] = 1.0f / lsum[rg][r];
#pragma unroll
  for (int rg = 0; rg < 2; rg++)
#pragma unroll
    for (int dt = 0; dt < 8; dt++)
#pragma unroll
      for (int r = 0; r < 4; r++)
        ob[(size_t)(bi * 2048 + q0w + rg * 16 + quad * 4 + r) * 2048 + h * 128 + dt * 16 + l16] =
            f2bf(o[rg][dt][r] * inv[rg][r]);
}

extern "C" void kernel_launch(void* const* d_in, const int* in_sizes, int n_in,
                              void* d_out, int out_size, void* d_ws, size_t ws_size,
                              hipStream_t stream) {
  const float* x = (const float*)d_in[0];
  const float* wqkv = (const float*)d_in[1];
  const float* wout = (const float*)d_in[2];
  // d_in[3] = mask, unused (causal analytically)
  char* ws = (char*)d_ws;
  const size_t MiB = 1ull << 20;
  unsigned short* xb    = (unsigned short*)(ws + 0);         // [4096,2048] bf16   16 MiB
  unsigned short* wqkvT = (unsigned short*)(ws + 16 * MiB);  // [6144,2048] bf16   24 MiB
  unsigned short* woutT = (unsigned short*)(ws + 40 * MiB);  // [2048,2048] bf16    8 MiB
  unsigned short* qb    = (unsigned short*)(ws + 48 * MiB);  // [32,2048,128] bf16 16 MiB
  unsigned short* kb    = (unsigned short*)(ws + 64 * MiB);  // [32,2048,128]      16 MiB
  unsigned short* vtb   = (unsigned short*)(ws + 80 * MiB);  // [32,128,2048]      16 MiB
  unsigned short* attnb = (unsigned short*)(ws + 96 * MiB);  // [4096,2048] bf16   16 MiB
  float* outF = (float*)d_out;

  prep_k<<<12288, 256, 0, stream>>>(x, wqkv, wout, xb, wqkvT, woutT);
  gemm_bt_k<0><<<dim3(48, 32), 256, 0, stream>>>(xb, wqkvT, 2048, 6144, nullptr, qb, kb, vtb);
  attn_k<<<512, 256, 0, stream>>>(qb, kb, vtb, attnb);
  gemm_bt_k<1><<<dim3(16, 32), 256, 0, stream>>>(attnb, woutT, 2048, 2048, outF,
                                                 nullptr, nullptr, nullptr);
}